// Round 1
// baseline (717.078 us; speedup 1.0000x reference)
//
#include <hip/hip_runtime.h>
#include <math.h>

#define T_DIM 32
#define H_DIM 1024
#define D_INNER 2048
#define D_STATE 128
#define NHEADS 32
#define HEADDIM 64
#define CONV_DIM 2304
#define D_IN_PROJ 4384
#define ASIZE_ 16384

__device__ __forceinline__ float wave_sum(float v) {
#pragma unroll
    for (int off = 32; off > 0; off >>= 1) v += __shfl_xor(v, off, 64);
    return v;
}
__device__ __forceinline__ float sigf(float x) { return 1.f / (1.f + expf(-x)); }
__device__ __forceinline__ float siluf(float x) { return x / (1.f + expf(-x)); }
__device__ __forceinline__ float softplusf(float x) { return x > 20.f ? x : log1pf(expf(x)); }

// ---------------- GEMV: one wave per row (good for large M, modest K) ----------------
template <int ACT>  // 0 none, 1 relu, 2 sigmoid
__global__ void gemv_wpr(const float* __restrict__ W, const float* __restrict__ x,
                         const float* __restrict__ b, float* __restrict__ out,
                         int M, int K) {
    int wid = threadIdx.x >> 6, lane = threadIdx.x & 63;
    int row = blockIdx.x * 4 + wid;
    if (row >= M) return;
    const float* wr = W + (size_t)row * K;
    float acc = 0.f;
    for (int k = lane * 4; k < K; k += 256) {
        float4 wv = *(const float4*)(wr + k);
        float4 xv = *(const float4*)(x + k);
        acc += wv.x * xv.x + wv.y * xv.y + wv.z * xv.z + wv.w * xv.w;
    }
    acc = wave_sum(acc);
    if (lane == 0) {
        float v = acc + b[row];
        if (ACT == 1) v = fmaxf(v, 0.f);
        if (ACT == 2) v = sigf(v);
        out[row] = v;
    }
}

// ---------------- GEMV: one 256-thread block per row (large K = 32768) ----------------
__global__ void gemv_bpr_relu(const float* __restrict__ W, const float* __restrict__ x,
                              const float* __restrict__ b, float* __restrict__ out, int K) {
    int row = blockIdx.x;
    const float* wr = W + (size_t)row * K;
    float acc = 0.f;
    for (int k = threadIdx.x * 4; k < K; k += 1024) {
        float4 wv = *(const float4*)(wr + k);
        float4 xv = *(const float4*)(x + k);
        acc += wv.x * xv.x + wv.y * xv.y + wv.z * xv.z + wv.w * xv.w;
    }
    acc = wave_sum(acc);
    __shared__ float ws4[4];
    int wid = threadIdx.x >> 6, lane = threadIdx.x & 63;
    if (lane == 0) ws4[wid] = acc;
    __syncthreads();
    if (threadIdx.x == 0)
        out[row] = fmaxf(ws4[0] + ws4[1] + ws4[2] + ws4[3] + b[row], 0.f);
}

// ---------------- skinny GEMM: out[t][j] += dot(W[j][kchunk], U[t][kchunk]) ----------------
// thread = one W row j; U chunk staged in LDS (reads are wave-uniform -> broadcast, conflict-free)
#define KC_IN 128
__global__ void gemm_in_k(const float* __restrict__ W, const float* __restrict__ U,
                          float* __restrict__ out, int M) {
    const int K = H_DIM;
    __shared__ float4 Ul[T_DIM][KC_IN / 4];
    int kbase = blockIdx.y * KC_IN;
    for (int i = threadIdx.x; i < T_DIM * (KC_IN / 4); i += 256) {
        int t = i >> 5, c4 = i & 31;
        Ul[t][c4] = *(const float4*)(U + t * K + kbase + c4 * 4);
    }
    __syncthreads();
    int j = blockIdx.x * 256 + threadIdx.x;
    if (j >= M) return;
    const float* wr = W + (size_t)j * K + kbase;
    float acc[T_DIM];
#pragma unroll
    for (int t = 0; t < T_DIM; t++) acc[t] = 0.f;
#pragma unroll 8
    for (int c4 = 0; c4 < KC_IN / 4; c4++) {
        float4 wv = *(const float4*)(wr + c4 * 4);
#pragma unroll
        for (int t = 0; t < T_DIM; t++) {
            float4 uv = Ul[t][c4];
            acc[t] = fmaf(wv.x, uv.x, acc[t]);
            acc[t] = fmaf(wv.y, uv.y, acc[t]);
            acc[t] = fmaf(wv.z, uv.z, acc[t]);
            acc[t] = fmaf(wv.w, uv.w, acc[t]);
        }
    }
#pragma unroll
    for (int t = 0; t < T_DIM; t++) atomicAdd(&out[t * M + j], acc[t]);
}

// Wout GEMM: also computes the RMSNorm scale from scan's per-block partial sums and
// folds scale*normw into the staged U tile; also zeroes zx for the next layer's gemm_in.
#define KC_OUT 64
__global__ void gemm_out_k(const float* __restrict__ W, const float* __restrict__ yg,
                           const float* __restrict__ psum, const float* __restrict__ normw,
                           float* __restrict__ out, float* __restrict__ zx_zero) {
    const int K = D_INNER;
    __shared__ float4 Ul[T_DIM][KC_OUT / 4];
    __shared__ float scale_s[T_DIM];
    __shared__ float ps8[8][T_DIM];
    {
        int t = threadIdx.x & 31, bc = threadIdx.x >> 5;
        float s = 0.f;
        for (int bb = bc; bb < 512; bb += 8) s += psum[bb * 32 + t];
        ps8[bc][t] = s;
    }
    __syncthreads();
    if (threadIdx.x < 32) {
        float tot = 0.f;
#pragma unroll
        for (int i = 0; i < 8; i++) tot += ps8[i][threadIdx.x];
        scale_s[threadIdx.x] = 1.f / sqrtf(tot * (1.f / (float)D_INNER) + 1e-5f);
    }
    __syncthreads();
    int kbase = blockIdx.y * KC_OUT;
    for (int i = threadIdx.x; i < T_DIM * (KC_OUT / 4); i += 256) {
        int t = i >> 4, c4 = i & 15;
        int k = kbase + c4 * 4;
        float4 v = *(const float4*)(yg + t * K + k);
        float4 nw = *(const float4*)(normw + k);
        float sc = scale_s[t];
        v.x *= sc * nw.x; v.y *= sc * nw.y; v.z *= sc * nw.z; v.w *= sc * nw.w;
        Ul[t][c4] = v;
    }
    __syncthreads();
    {   // zero zx for the next layer's gemm_in atomics (safe: scan already consumed it)
        int nth = gridDim.x * gridDim.y * 256;
        int gid = (blockIdx.y * gridDim.x + blockIdx.x) * 256 + threadIdx.x;
        for (int i = gid; i < T_DIM * D_IN_PROJ; i += nth) zx_zero[i] = 0.f;
    }
    int j = blockIdx.x * 256 + threadIdx.x;  // gridDim.x = 4 -> j < 1024, no guard
    const float* wr = W + (size_t)j * K + kbase;
    float acc[T_DIM];
#pragma unroll
    for (int t = 0; t < T_DIM; t++) acc[t] = 0.f;
#pragma unroll 8
    for (int c4 = 0; c4 < KC_OUT / 4; c4++) {
        float4 wv = *(const float4*)(wr + c4 * 4);
#pragma unroll
        for (int t = 0; t < T_DIM; t++) {
            float4 uv = Ul[t][c4];
            acc[t] = fmaf(wv.x, uv.x, acc[t]);
            acc[t] = fmaf(wv.y, uv.y, acc[t]);
            acc[t] = fmaf(wv.z, uv.z, acc[t]);
            acc[t] = fmaf(wv.w, uv.w, acc[t]);
        }
    }
#pragma unroll
    for (int t = 0; t < T_DIM; t++) atomicAdd(&out[t * H_DIM + j], acc[t]);
}

// ---------------- conv + silu + softplus + SSM scan + gate; wave = one (head, p) ----------------
__global__ void scan_k(const float* __restrict__ zx, const float* __restrict__ convw,
                       const float* __restrict__ convb, const float* __restrict__ dtbias,
                       const float* __restrict__ Alog, const float* __restrict__ Dp,
                       float* __restrict__ yg, float* __restrict__ psum,
                       float* __restrict__ seq_zero) {
    __shared__ float BC[T_DIM][256];
    __shared__ float ps_l[T_DIM];
    int tid = threadIdx.x;
    if (tid < 64) seq_zero[blockIdx.x * 64 + tid] = 0.f;  // zero next seq buffer
    if (tid < T_DIM) ps_l[tid] = 0.f;
    {   // B/C channels: conv-space c = 2048+tid  ->  zx column 4096+tid
        int c = 2048 + tid;
        int col = D_INNER + c;
        float w0 = convw[c * 4], w1 = convw[c * 4 + 1], w2 = convw[c * 4 + 2], w3 = convw[c * 4 + 3];
        float cb = convb[c];
        float xm3 = 0.f, xm2 = 0.f, xm1 = 0.f;
#pragma unroll
        for (int t = 0; t < T_DIM; t++) {
            float x0 = zx[t * D_IN_PROJ + col];
            float v = fmaf(xm3, w0, fmaf(xm2, w1, fmaf(xm1, w2, fmaf(x0, w3, cb))));
            BC[t][tid] = siluf(v);
            xm3 = xm2; xm2 = xm1; xm1 = x0;
        }
    }
    __syncthreads();
    int wid = tid >> 6, lane = tid & 63;
    int hp = blockIdx.x * 4 + wid;   // 0..2047
    int head = hp >> 6;
    int t0 = lane & 31;              // lane's owned timestep (lanes 32..63 mirror)
    float dtv, dAv, xhv;
    {
        float draw = zx[t0 * D_IN_PROJ + (D_IN_PROJ - NHEADS) + head] + dtbias[head];
        dtv = softplusf(draw);
        dAv = expf(dtv * (-expf(Alog[head])));
        int c = hp;  // xh channel in conv space
        float w0 = convw[c * 4], w1 = convw[c * 4 + 1], w2 = convw[c * 4 + 2], w3 = convw[c * 4 + 3];
        float a = fmaf(zx[t0 * D_IN_PROJ + 2048 + c], w3, convb[c]);
        if (t0 >= 1) a = fmaf(zx[(t0 - 1) * D_IN_PROJ + 2048 + c], w2, a);
        if (t0 >= 2) a = fmaf(zx[(t0 - 2) * D_IN_PROJ + 2048 + c], w1, a);
        if (t0 >= 3) a = fmaf(zx[(t0 - 3) * D_IN_PROJ + 2048 + c], w0, a);
        xhv = siluf(a);
    }
    float coef_r = dtv * xhv;
    float h0 = 0.f, h1 = 0.f, ykeep = 0.f;
    for (int t = 0; t < T_DIM; t++) {
        float dA_t = __shfl(dAv, t, 64);
        float cf = __shfl(coef_r, t, 64);
        float B0 = BC[t][lane], B1 = BC[t][64 + lane];
        float C0 = BC[t][128 + lane], C1 = BC[t][192 + lane];
        h0 = fmaf(h0, dA_t, cf * B0);
        h1 = fmaf(h1, dA_t, cf * B1);
        float part = wave_sum(fmaf(h0, C0, h1 * C1));
        if (lane == t) ykeep = part;
    }
    if (lane < T_DIM) {
        float y = fmaf(Dp[head], xhv, ykeep);
        float z = zx[t0 * D_IN_PROJ + hp];
        float g = y * siluf(z);
        yg[t0 * D_INNER + hp] = g;
        atomicAdd(&ps_l[t0], g * g);
    }
    __syncthreads();
    if (tid < T_DIM) psum[blockIdx.x * T_DIM + tid] = ps_l[tid];
}

extern "C" void kernel_launch(void* const* d_in, const int* in_sizes, int n_in,
                              void* d_out, int out_size, void* d_ws, size_t ws_size,
                              hipStream_t stream) {
    const float* x = (const float*)d_in[0];
    const float* w1 = (const float*)d_in[1];
    const float* b1 = (const float*)d_in[2];
    const float* w2 = (const float*)d_in[3];
    const float* b2 = (const float*)d_in[4];
    const float* mWin = (const float*)d_in[5];
    const float* mconvw = (const float*)d_in[6];
    const float* mconvb = (const float*)d_in[7];
    const float* mdtb = (const float*)d_in[8];
    const float* mAlog = (const float*)d_in[9];
    const float* mD = (const float*)d_in[10];
    const float* mnw = (const float*)d_in[11];
    const float* mWout = (const float*)d_in[12];
    const float* w3 = (const float*)d_in[13];
    const float* b3 = (const float*)d_in[14];
    const float* w4 = (const float*)d_in[15];
    const float* b4 = (const float*)d_in[16];
    float* out = (float*)d_out;

    float* ws = (float*)d_ws;
    float* zx = ws;                        // 32*4384
    float* seqA = zx + T_DIM * D_IN_PROJ;  // 32*1024
    float* seqB = seqA + T_DIM * H_DIM;    // 32*1024
    float* yg = seqB + T_DIM * H_DIM;      // 32*2048
    float* ps = yg + T_DIM * D_INNER;      // 512*32
    float* h1 = ps + 512 * T_DIM;          // 1024
    float* a3 = h1 + H_DIM;                // 1024

    hipMemsetAsync(zx, 0, (size_t)T_DIM * D_IN_PROJ * sizeof(float), stream);

    gemv_wpr<1><<<256, 256, 0, stream>>>(w1, x, b1, h1, H_DIM, 4096);
    gemv_wpr<0><<<8192, 256, 0, stream>>>(w2, h1, b2, seqA, T_DIM * H_DIM, H_DIM);

    float* cur = seqA;
    float* nxt = seqB;
    for (int l = 0; l < 4; l++) {
        dim3 gi((D_IN_PROJ + 255) / 256, H_DIM / KC_IN);  // (18, 8)
        gemm_in_k<<<gi, 256, 0, stream>>>(mWin + (size_t)l * D_IN_PROJ * H_DIM, cur, zx, D_IN_PROJ);
        scan_k<<<512, 256, 0, stream>>>(zx, mconvw + l * CONV_DIM * 4, mconvb + l * CONV_DIM,
                                        mdtb + l * NHEADS, mAlog + l * NHEADS, mD + l * NHEADS,
                                        yg, ps, nxt);
        dim3 go(H_DIM / 256, D_INNER / KC_OUT);  // (4, 32)
        gemm_out_k<<<go, 256, 0, stream>>>(mWout + (size_t)l * H_DIM * D_INNER, yg, ps,
                                           mnw + l * D_INNER, nxt, zx);
        float* tmp = cur; cur = nxt; nxt = tmp;
    }
    gemv_bpr_relu<<<1024, 256, 0, stream>>>(w3, cur, b3, a3, T_DIM * H_DIM);
    gemv_wpr<2><<<4096, 256, 0, stream>>>(w4, a3, b4, out, ASIZE_, H_DIM);
}